// Round 2
// baseline (394.141 us; speedup 1.0000x reference)
//
#include <hip/hip_runtime.h>
#include <cstdint>
#include <cstddef>

static constexpr int HW_  = 16384;  // h*w
static constexpr int NB_  = 32;     // batch
static constexpr int NN_  = 64;     // n
static constexpr int BKI_ = 64;     // K-tile staged in LDS

// Swizzled word index inside a [BKI][64] k-major LDS tile.
// Block-of-4 XOR swizzle, key = (k>>2)&15:
//  - staging ds_write_b32: 2-way bank conflict (free)
//  - frag ds_read_b128 at fixed k: conflict-free / 2-way
__device__ __forceinline__ int lds_word(int k, int i) {
    return (k << 6) + ((((i >> 2) ^ ((k >> 2) & 15)) << 2) | (i & 3));
}

__global__ void gram_kernel(const float* __restrict__ masks,
                            float* __restrict__ gram_part,
                            float* __restrict__ s_part,
                            int NC, int KC) {
    __shared__ float tile[BKI_ * NN_];   // 16 KiB
    const int bx = blockIdx.x;
    const int b  = bx / NC;
    const int c  = bx - b * NC;
    const int t  = threadIdx.x;          // 64 threads = 1 wave
    const int ty = t >> 3, tx = t & 7;   // 8x8 thread grid, 8x8 outputs each
    const float* mb = masks + (size_t)b * (NN_ * HW_) + (size_t)c * KC;

    float acc[8][8];
    float sreg[8];
#pragma unroll
    for (int r = 0; r < 8; ++r) {
        sreg[r] = 0.f;
#pragma unroll
        for (int q = 0; q < 8; ++q) acc[r][q] = 0.f;
    }

    for (int kt = 0; kt < KC; kt += BKI_) {
        __syncthreads();  // previous tile's readers done
        // ---- stage 64 rows x BKI k (k-major, swizzled), fuse clip transform
#pragma unroll
        for (int it = 0; it < 16; ++it) {
            const int f  = it * 64 + t;
            const int i  = f >> 4;        // row 0..63
            const int k4 = f & 15;        // float4 index along k
            const float4 v = *reinterpret_cast<const float4*>(
                mb + (size_t)i * HW_ + kt + k4 * 4);
            const int kl = k4 * 4;
            tile[lds_word(kl + 0, i)] = fmaxf(0.f, (v.x + 1.f) * 0.5f);
            tile[lds_word(kl + 1, i)] = fmaxf(0.f, (v.y + 1.f) * 0.5f);
            tile[lds_word(kl + 2, i)] = fmaxf(0.f, (v.z + 1.f) * 0.5f);
            tile[lds_word(kl + 3, i)] = fmaxf(0.f, (v.w + 1.f) * 0.5f);
        }
        __syncthreads();
        // ---- 8x8 register-tile SYRK over this K-tile
#pragma unroll 4
        for (int k = 0; k < BKI_; ++k) {
            const int base = (k << 6);
            const int key  = (k >> 2) & 15;
            const float4 a0 = *reinterpret_cast<const float4*>(&tile[base + (((2 * ty)     ^ key) << 2)]);
            const float4 a1 = *reinterpret_cast<const float4*>(&tile[base + (((2 * ty + 1) ^ key) << 2)]);
            const float4 b0 = *reinterpret_cast<const float4*>(&tile[base + (((2 * tx)     ^ key) << 2)]);
            const float4 b1 = *reinterpret_cast<const float4*>(&tile[base + (((2 * tx + 1) ^ key) << 2)]);
            const float av[8] = {a0.x, a0.y, a0.z, a0.w, a1.x, a1.y, a1.z, a1.w};
            const float bv[8] = {b0.x, b0.y, b0.z, b0.w, b1.x, b1.y, b1.z, b1.w};
#pragma unroll
            for (int r = 0; r < 8; ++r) sreg[r] += av[r];
#pragma unroll
            for (int r = 0; r < 8; ++r)
#pragma unroll
                for (int q = 0; q < 8; ++q) acc[r][q] += av[r] * bv[q];
        }
    }

    // ---- write partial gram (64x64) and partial row sums for this (b, chunk)
    float* gp = gram_part + (size_t)(c * NB_ + b) * (NN_ * NN_);
#pragma unroll
    for (int r = 0; r < 8; ++r) {
        const int row = 8 * ty + r;
        const float4 o0 = make_float4(acc[r][0], acc[r][1], acc[r][2], acc[r][3]);
        const float4 o1 = make_float4(acc[r][4], acc[r][5], acc[r][6], acc[r][7]);
        *reinterpret_cast<float4*>(gp + row * NN_ + 8 * tx)     = o0;
        *reinterpret_cast<float4*>(gp + row * NN_ + 8 * tx + 4) = o1;
    }
    if (tx == 0) {
#pragma unroll
        for (int r = 0; r < 8; ++r)
            s_part[(size_t)c * (NB_ * NN_) + b * NN_ + 8 * ty + r] = sreg[r];
    }
}

__global__ void s_reduce_kernel(const float* __restrict__ s_part,
                                float* __restrict__ s_full, int NC) {
    const int b = blockIdx.x;
    const int t = threadIdx.x;
    float v = 0.f;
    for (int c = 0; c < NC; ++c)
        v += s_part[(size_t)c * (NB_ * NN_) + b * NN_ + t];
    s_full[b * NN_ + t] = v;
}

__global__ void loss_kernel(const float* __restrict__ gram_part,
                            const float* __restrict__ s_full,
                            const int* __restrict__ nodes,
                            float* __restrict__ num_part,
                            float* __restrict__ den_part,
                            int NC) {
    const int i = blockIdx.x;   // row
    const int j = threadIdx.x;  // col, 64 threads = 1 wave
    float acc = 0.f;
    for (int b = 0; b < NB_; ++b) {
        float g = 0.f;
        for (int c = 0; c < NC; ++c)
            g += gram_part[(size_t)(c * NB_ + b) * (NN_ * NN_) + i * NN_ + j];
        const float si = s_full[b * NN_ + i];
        const float sj = s_full[b * NN_ + j];
        acc += g / fminf(si, sj);
    }
    const float cr = acc * (1.0f / NB_);

    const int ni = nodes[i];
    const int nj = nodes[j];
    const int ti = (ni < 7) ? 0 : ((ni < 9) ? 1 : 2);  // N_SEPARATE=7, +N_FLEXIBLE=9
    const int tj = (nj < 7) ? 0 : ((nj < 9) ? 1 : 2);
    const bool has_f = (ti == 1) || (tj == 1);
    const bool has_a = (ti == 2) || (tj == 2);
    const bool include = !(has_f && !has_a);
    const float beta = ((ti == 2) != (tj == 2)) ? 1.f : 0.f;
    const float w = (include && (j > i)) ? 1.f : 0.f;

    float num = w * fabsf(beta - cr);
    float den = w;
#pragma unroll
    for (int off = 32; off >= 1; off >>= 1) {
        num += __shfl_xor(num, off, 64);
        den += __shfl_xor(den, off, 64);
    }
    if (j == 0) {
        num_part[i] = num;
        den_part[i] = den;
    }
}

__global__ void final_kernel(const float* __restrict__ num_part,
                             const float* __restrict__ den_part,
                             float* __restrict__ out) {
    const int t = threadIdx.x;
    float num = num_part[t];
    float den = den_part[t];
#pragma unroll
    for (int off = 32; off >= 1; off >>= 1) {
        num += __shfl_xor(num, off, 64);
        den += __shfl_xor(den, off, 64);
    }
    if (t == 0) out[0] = num / den;
}

extern "C" void kernel_launch(void* const* d_in, const int* in_sizes, int n_in,
                              void* d_out, int out_size, void* d_ws, size_t ws_size,
                              hipStream_t stream) {
    const float* masks = (const float*)d_in[0];
    const int* nodes = (const int*)d_in[1];   // harness passes integers as int32
    float* out = (float*)d_out;

    // Pick K-chunk count NC that fits the workspace (partials are fp32, no atomics
    // => deterministic). NC=32 needs ~17 MiB.
    const size_t ws_floats = ws_size / sizeof(float);
    int NC = 32;
    while (NC > 1) {
        const size_t need = (size_t)NC * NB_ * NN_ * NN_   // gram partials
                          + (size_t)NC * NB_ * NN_         // s partials
                          + (size_t)NB_ * NN_              // s_full
                          + 2 * NN_;                       // loss partials
        if (need <= ws_floats) break;
        NC >>= 1;
    }
    const int KC = HW_ / NC;

    float* gram_part = (float*)d_ws;
    float* s_part    = gram_part + (size_t)NC * NB_ * NN_ * NN_;
    float* s_full    = s_part    + (size_t)NC * NB_ * NN_;
    float* num_part  = s_full    + (size_t)NB_ * NN_;
    float* den_part  = num_part  + NN_;

    gram_kernel<<<NB_ * NC, 64, 0, stream>>>(masks, gram_part, s_part, NC, KC);
    s_reduce_kernel<<<NB_, 64, 0, stream>>>(s_part, s_full, NC);
    loss_kernel<<<NN_, 64, 0, stream>>>(gram_part, s_full, nodes, num_part, den_part, NC);
    final_kernel<<<1, 64, 0, stream>>>(num_part, den_part, out);
}

// Round 3
// 152.869 us; speedup vs baseline: 2.5783x; 2.5783x over previous
//
#include <hip/hip_runtime.h>
#include <cstdint>
#include <cstddef>

static constexpr int HW_  = 16384;  // h*w
static constexpr int NB_  = 32;     // batch
static constexpr int NN_  = 64;     // n
static constexpr int BKI_ = 64;     // K-tile staged in LDS

// Swizzled word index inside a [BKI][64] k-major LDS tile.
__device__ __forceinline__ int lds_word(int k, int i) {
    return (k << 6) + ((((i >> 2) ^ ((k >> 2) & 15)) << 2) | (i & 3));
}

__global__ void gram_kernel(const float* __restrict__ masks,
                            float* __restrict__ gram_part,
                            float* __restrict__ s_part,
                            int NC, int KC) {
    __shared__ float tile[BKI_ * NN_];   // 16 KiB
    const int bx = blockIdx.x;
    const int b  = bx / NC;
    const int c  = bx - b * NC;
    const int t  = threadIdx.x;          // 64 threads = 1 wave
    const int ty = t >> 3, tx = t & 7;   // 8x8 thread grid, 8x8 outputs each
    const float* mb = masks + (size_t)b * (NN_ * HW_) + (size_t)c * KC;

    float acc[8][8];
    float sreg[8];
#pragma unroll
    for (int r = 0; r < 8; ++r) {
        sreg[r] = 0.f;
#pragma unroll
        for (int q = 0; q < 8; ++q) acc[r][q] = 0.f;
    }

    for (int kt = 0; kt < KC; kt += BKI_) {
        __syncthreads();
#pragma unroll
        for (int it = 0; it < 16; ++it) {
            const int f  = it * 64 + t;
            const int i  = f >> 4;
            const int k4 = f & 15;
            const float4 v = *reinterpret_cast<const float4*>(
                mb + (size_t)i * HW_ + kt + k4 * 4);
            const int kl = k4 * 4;
            tile[lds_word(kl + 0, i)] = fmaxf(0.f, (v.x + 1.f) * 0.5f);
            tile[lds_word(kl + 1, i)] = fmaxf(0.f, (v.y + 1.f) * 0.5f);
            tile[lds_word(kl + 2, i)] = fmaxf(0.f, (v.z + 1.f) * 0.5f);
            tile[lds_word(kl + 3, i)] = fmaxf(0.f, (v.w + 1.f) * 0.5f);
        }
        __syncthreads();
#pragma unroll 4
        for (int k = 0; k < BKI_; ++k) {
            const int base = (k << 6);
            const int key  = (k >> 2) & 15;
            const float4 a0 = *reinterpret_cast<const float4*>(&tile[base + (((2 * ty)     ^ key) << 2)]);
            const float4 a1 = *reinterpret_cast<const float4*>(&tile[base + (((2 * ty + 1) ^ key) << 2)]);
            const float4 b0 = *reinterpret_cast<const float4*>(&tile[base + (((2 * tx)     ^ key) << 2)]);
            const float4 b1 = *reinterpret_cast<const float4*>(&tile[base + (((2 * tx + 1) ^ key) << 2)]);
            const float av[8] = {a0.x, a0.y, a0.z, a0.w, a1.x, a1.y, a1.z, a1.w};
            const float bv[8] = {b0.x, b0.y, b0.z, b0.w, b1.x, b1.y, b1.z, b1.w};
#pragma unroll
            for (int r = 0; r < 8; ++r) sreg[r] += av[r];
#pragma unroll
            for (int r = 0; r < 8; ++r)
#pragma unroll
                for (int q = 0; q < 8; ++q) acc[r][q] += av[r] * bv[q];
        }
    }

    float* gp = gram_part + (size_t)(c * NB_ + b) * (NN_ * NN_);
#pragma unroll
    for (int r = 0; r < 8; ++r) {
        const int row = 8 * ty + r;
        const float4 o0 = make_float4(acc[r][0], acc[r][1], acc[r][2], acc[r][3]);
        const float4 o1 = make_float4(acc[r][4], acc[r][5], acc[r][6], acc[r][7]);
        *reinterpret_cast<float4*>(gp + row * NN_ + 8 * tx)     = o0;
        *reinterpret_cast<float4*>(gp + row * NN_ + 8 * tx + 4) = o1;
    }
    if (tx == 0) {
#pragma unroll
        for (int r = 0; r < 8; ++r)
            s_part[(size_t)c * (NB_ * NN_) + b * NN_ + 8 * ty + r] = sreg[r];
    }
}

__global__ void s_reduce_kernel(const float* __restrict__ s_part,
                                float* __restrict__ s_full, int NC) {
    const int b = blockIdx.x;
    const int t = threadIdx.x;
    float v = 0.f;
    for (int c = 0; c < NC; ++c)
        v += s_part[(size_t)c * (NB_ * NN_) + b * NN_ + t];
    s_full[b * NN_ + t] = v;
}

// Stage 1 of the epilogue: for each (b, ij) sum gram partials over c
// (coalesced: consecutive threads = consecutive ij), divide by min(si,sj).
__global__ void cr_weight_kernel(const float* __restrict__ gram_part,
                                 const float* __restrict__ s_full,
                                 float* __restrict__ wq, int NC) {
    const int b  = blockIdx.x;                       // 0..31
    const int ij = blockIdx.y * 256 + threadIdx.x;   // 0..4095
    float g = 0.f;
#pragma unroll 8
    for (int c = 0; c < NC; ++c)
        g += gram_part[(size_t)(c * NB_ + b) * (NN_ * NN_) + ij];
    const int i = ij >> 6, j = ij & 63;
    const float si = s_full[b * NN_ + i];
    const float sj = s_full[b * NN_ + j];
    wq[(size_t)b * (NN_ * NN_) + ij] = g / fminf(si, sj);
}

// Stage 2: mean over b, apply beta/weight mask, block-reduce num/den.
__global__ void loss2_kernel(const float* __restrict__ wq,
                             const int* __restrict__ nodes,
                             float* __restrict__ num_part,
                             float* __restrict__ den_part) {
    __shared__ float red[8];
    const int ij = blockIdx.x * 256 + threadIdx.x;
    float acc = 0.f;
#pragma unroll
    for (int b = 0; b < NB_; ++b)
        acc += wq[(size_t)b * (NN_ * NN_) + ij];
    const float cr = acc * (1.0f / NB_);

    const int i = ij >> 6, j = ij & 63;
    const int ni = nodes[i];
    const int nj = nodes[j];
    const int ti = (ni < 7) ? 0 : ((ni < 9) ? 1 : 2);
    const int tj = (nj < 7) ? 0 : ((nj < 9) ? 1 : 2);
    const bool has_f = (ti == 1) || (tj == 1);
    const bool has_a = (ti == 2) || (tj == 2);
    const bool include = !(has_f && !has_a);
    const float beta = ((ti == 2) != (tj == 2)) ? 1.f : 0.f;
    const float w = (include && (j > i)) ? 1.f : 0.f;

    float num = w * fabsf(beta - cr);
    float den = w;
#pragma unroll
    for (int off = 32; off >= 1; off >>= 1) {
        num += __shfl_xor(num, off, 64);
        den += __shfl_xor(den, off, 64);
    }
    const int wave = threadIdx.x >> 6;   // 0..3
    const int lane = threadIdx.x & 63;
    if (lane == 0) { red[wave] = num; red[4 + wave] = den; }
    __syncthreads();
    if (threadIdx.x == 0) {
        num_part[blockIdx.x] = red[0] + red[1] + red[2] + red[3];
        den_part[blockIdx.x] = red[4] + red[5] + red[6] + red[7];
    }
}

__global__ void final_kernel(const float* __restrict__ num_part,
                             const float* __restrict__ den_part,
                             float* __restrict__ out) {
    const int t = threadIdx.x;   // 64 threads; 16 valid partials
    float num = (t < 16) ? num_part[t] : 0.f;
    float den = (t < 16) ? den_part[t] : 0.f;
#pragma unroll
    for (int off = 32; off >= 1; off >>= 1) {
        num += __shfl_xor(num, off, 64);
        den += __shfl_xor(den, off, 64);
    }
    if (t == 0) out[0] = num / den;
}

extern "C" void kernel_launch(void* const* d_in, const int* in_sizes, int n_in,
                              void* d_out, int out_size, void* d_ws, size_t ws_size,
                              hipStream_t stream) {
    const float* masks = (const float*)d_in[0];
    const int* nodes = (const int*)d_in[1];   // harness passes integers as int32
    float* out = (float*)d_out;

    const size_t ws_floats = ws_size / sizeof(float);
    int NC = 32;
    while (NC > 1) {
        const size_t need = (size_t)NC * NB_ * NN_ * NN_   // gram partials
                          + (size_t)NC * NB_ * NN_         // s partials
                          + (size_t)NB_ * NN_              // s_full
                          + (size_t)NB_ * NN_ * NN_        // wq
                          + 2 * 16;                        // loss partials
        if (need <= ws_floats) break;
        NC >>= 1;
    }
    const int KC = HW_ / NC;

    float* gram_part = (float*)d_ws;
    float* s_part    = gram_part + (size_t)NC * NB_ * NN_ * NN_;
    float* s_full    = s_part    + (size_t)NC * NB_ * NN_;
    float* wq        = s_full    + (size_t)NB_ * NN_;
    float* num_part  = wq        + (size_t)NB_ * NN_ * NN_;
    float* den_part  = num_part  + 16;

    gram_kernel<<<NB_ * NC, 64, 0, stream>>>(masks, gram_part, s_part, NC, KC);
    s_reduce_kernel<<<NB_, 64, 0, stream>>>(s_part, s_full, NC);
    cr_weight_kernel<<<dim3(NB_, (NN_ * NN_) / 256), 256, 0, stream>>>(gram_part, s_full, wq, NC);
    loss2_kernel<<<(NN_ * NN_) / 256, 256, 0, stream>>>(wq, nodes, num_part, den_part);
    final_kernel<<<1, 64, 0, stream>>>(num_part, den_part, out);
}

// Round 4
// 45.594 us; speedup vs baseline: 8.6446x; 3.3528x over previous
//
#include <hip/hip_runtime.h>
#include <cstdint>
#include <cstddef>

static constexpr int HW_ = 16384;  // h*w
static constexpr int NB_ = 32;     // batch
static constexpr int NN_ = 64;     // n
static constexpr int BK_ = 64;     // k per staged LDS tile

typedef short bfrag  __attribute__((ext_vector_type(8)));  // 8 bf16 (4 VGPRs)
typedef float f32x4  __attribute__((ext_vector_type(4)));  // MFMA accumulator

// fp32 -> bf16, round-to-nearest-even (unbiased; truncation would bias the
// K=16384 product sum low by ~0.5%)
__device__ __forceinline__ unsigned short f2bf_rne(float x) {
    unsigned u = __builtin_bit_cast(unsigned, x);
    return (unsigned short)((u + 0x7FFFu + ((u >> 16) & 1u)) >> 16);
}

// XOR-swizzled bf16-element index in a row-major [64 rows][BK_=64 k] bf16 tile
// (128 B rows). byte ^= (row&7)<<4 : spreads the 16-rows-at-same-column MFMA
// fragment reads across 8 16B slots (G4 pattern). Same involution on write+read.
__device__ __forceinline__ int swz(int row, int k) {
    int byte = (row << 7) + (k << 1);
    byte ^= (row & 7) << 4;
    return byte >> 1;
}

__global__ __launch_bounds__(256) void gram_kernel(const float* __restrict__ masks,
                                                   float* __restrict__ gram_part,
                                                   float* __restrict__ s_part,
                                                   int NC, int KC) {
    __shared__ __align__(16) unsigned short lds[2][NN_ * BK_];  // 2 x 8 KiB bf16
    const int bx = blockIdx.x;
    const int b  = bx / NC;
    const int c  = bx - b * NC;
    const int t  = threadIdx.x;        // 256 threads = 4 waves
    const int l  = t & 63;
    const int w  = t >> 6;             // wave id: owns output rows [16w,16w+16)
    const int lrow = t >> 4;           // staging row base 0..15
    const int lk4  = t & 15;           // staging float4 index along k
    const float* mb = masks + (size_t)b * (NN_ * HW_) + (size_t)c * KC;
    const int NT = KC / BK_;

    f32x4 acc[4];
#pragma unroll
    for (int cb = 0; cb < 4; ++cb) acc[cb] = (f32x4){0.f, 0.f, 0.f, 0.f};
    float sreg[4] = {0.f, 0.f, 0.f, 0.f};
    float4 ld[4];

    // issue global loads for tile tt (raw fp32, no dependent ops -> loads stay
    // in flight under compute)
    auto stage_load = [&](int tt) {
        const float* src = mb + tt * BK_ + lk4 * 4;
#pragma unroll
        for (int p = 0; p < 4; ++p)
            ld[p] = *reinterpret_cast<const float4*>(src + (size_t)(lrow + 16 * p) * HW_);
    };
    // transform + s-accumulate + bf16-pack + swizzled ds_write (T14 late half)
    auto stage_write = [&](unsigned short* buf) {
#pragma unroll
        for (int p = 0; p < 4; ++p) {
            const float m0 = fmaxf(0.f, (ld[p].x + 1.f) * 0.5f);
            const float m1 = fmaxf(0.f, (ld[p].y + 1.f) * 0.5f);
            const float m2 = fmaxf(0.f, (ld[p].z + 1.f) * 0.5f);
            const float m3 = fmaxf(0.f, (ld[p].w + 1.f) * 0.5f);
            sreg[p] += (m0 + m1) + (m2 + m3);
            const ushort4 pk = make_ushort4(f2bf_rne(m0), f2bf_rne(m1),
                                            f2bf_rne(m2), f2bf_rne(m3));
            *reinterpret_cast<ushort4*>(&buf[swz(lrow + 16 * p, lk4 * 4)]) = pk;
        }
    };
    // 8 MFMA over one staged 64x64 tile; wave w: rows [16w,16w+16) x all 64 cols
    auto compute = [&](const unsigned short* buf) {
#pragma unroll
        for (int ks = 0; ks < BK_; ks += 32) {
            const int kb = ks + ((l >> 4) << 3);
            const bfrag a = *reinterpret_cast<const bfrag*>(&buf[swz((w << 4) + (l & 15), kb)]);
#pragma unroll
            for (int cb = 0; cb < 4; ++cb) {
                const bfrag bb = *reinterpret_cast<const bfrag*>(&buf[swz((cb << 4) + (l & 15), kb)]);
                acc[cb] = __builtin_amdgcn_mfma_f32_16x16x32_bf16(a, bb, acc[cb], 0, 0, 0);
            }
        }
    };

    stage_load(0);
    stage_write(lds[0]);
    __syncthreads();
    for (int tt = 0; tt < NT; ++tt) {
        const int cur = tt & 1;
        const bool more = (tt + 1 < NT);
        if (more) stage_load(tt + 1);     // issue early
        compute(lds[cur]);                // hide HBM latency under MFMA+ds_read
        if (more) stage_write(lds[cur ^ 1]);  // write late (readers drained at prev barrier)
        __syncthreads();
    }

    // C/D layout (m89-verified): col = lane&15, row = (lane>>4)*4 + reg
    float* gp = gram_part + (size_t)(c * NB_ + b) * (NN_ * NN_);
#pragma unroll
    for (int cb = 0; cb < 4; ++cb)
#pragma unroll
        for (int r = 0; r < 4; ++r) {
            const int i = (w << 4) + ((l >> 4) << 2) + r;
            const int j = (cb << 4) + (l & 15);
            gp[i * NN_ + j] = acc[cb][r];
        }
    // row-sums: lanes sharing l>>4 hold the same row-set, lk4 spans the k-range
#pragma unroll
    for (int p = 0; p < 4; ++p) {
        float v = sreg[p];
        v += __shfl_xor(v, 1, 64);
        v += __shfl_xor(v, 2, 64);
        v += __shfl_xor(v, 4, 64);
        v += __shfl_xor(v, 8, 64);
        if ((l & 15) == 0)
            s_part[(size_t)c * (NB_ * NN_) + b * NN_ + (lrow + 16 * p)] = v;
    }
}

__global__ void s_reduce_kernel(const float* __restrict__ s_part,
                                float* __restrict__ s_full, int NC) {
    const int b = blockIdx.x;
    const int t = threadIdx.x;
    float v = 0.f;
    for (int c = 0; c < NC; ++c)
        v += s_part[(size_t)c * (NB_ * NN_) + b * NN_ + t];
    s_full[b * NN_ + t] = v;
}

__global__ void cr_weight_kernel(const float* __restrict__ gram_part,
                                 const float* __restrict__ s_full,
                                 float* __restrict__ wq, int NC) {
    const int b  = blockIdx.x;                       // 0..31
    const int ij = blockIdx.y * 256 + threadIdx.x;   // 0..4095
    float g = 0.f;
#pragma unroll 8
    for (int c = 0; c < NC; ++c)
        g += gram_part[(size_t)(c * NB_ + b) * (NN_ * NN_) + ij];
    const int i = ij >> 6, j = ij & 63;
    const float si = s_full[b * NN_ + i];
    const float sj = s_full[b * NN_ + j];
    wq[(size_t)b * (NN_ * NN_) + ij] = g / fminf(si, sj);
}

__global__ void loss2_kernel(const float* __restrict__ wq,
                             const int* __restrict__ nodes,
                             float* __restrict__ num_part,
                             float* __restrict__ den_part) {
    __shared__ float red[8];
    const int ij = blockIdx.x * 256 + threadIdx.x;
    float acc = 0.f;
#pragma unroll
    for (int b = 0; b < NB_; ++b)
        acc += wq[(size_t)b * (NN_ * NN_) + ij];
    const float cr = acc * (1.0f / NB_);

    const int i = ij >> 6, j = ij & 63;
    const int ni = nodes[i];
    const int nj = nodes[j];
    const int ti = (ni < 7) ? 0 : ((ni < 9) ? 1 : 2);
    const int tj = (nj < 7) ? 0 : ((nj < 9) ? 1 : 2);
    const bool has_f = (ti == 1) || (tj == 1);
    const bool has_a = (ti == 2) || (tj == 2);
    const bool include = !(has_f && !has_a);
    const float beta = ((ti == 2) != (tj == 2)) ? 1.f : 0.f;
    const float wgt = (include && (j > i)) ? 1.f : 0.f;

    float num = wgt * fabsf(beta - cr);
    float den = wgt;
#pragma unroll
    for (int off = 32; off >= 1; off >>= 1) {
        num += __shfl_xor(num, off, 64);
        den += __shfl_xor(den, off, 64);
    }
    const int wave = threadIdx.x >> 6;
    const int lane = threadIdx.x & 63;
    if (lane == 0) { red[wave] = num; red[4 + wave] = den; }
    __syncthreads();
    if (threadIdx.x == 0) {
        num_part[blockIdx.x] = red[0] + red[1] + red[2] + red[3];
        den_part[blockIdx.x] = red[4] + red[5] + red[6] + red[7];
    }
}

__global__ void final_kernel(const float* __restrict__ num_part,
                             const float* __restrict__ den_part,
                             float* __restrict__ out) {
    const int t = threadIdx.x;   // 16 valid partials
    float num = (t < 16) ? num_part[t] : 0.f;
    float den = (t < 16) ? den_part[t] : 0.f;
#pragma unroll
    for (int off = 32; off >= 1; off >>= 1) {
        num += __shfl_xor(num, off, 64);
        den += __shfl_xor(den, off, 64);
    }
    if (t == 0) out[0] = num / den;
}

extern "C" void kernel_launch(void* const* d_in, const int* in_sizes, int n_in,
                              void* d_out, int out_size, void* d_ws, size_t ws_size,
                              hipStream_t stream) {
    const float* masks = (const float*)d_in[0];
    const int* nodes = (const int*)d_in[1];   // harness passes integers as int32
    float* out = (float*)d_out;

    const size_t ws_floats = ws_size / sizeof(float);
    int NC = 32;
    while (NC > 1) {
        const size_t need = (size_t)NC * NB_ * NN_ * NN_   // gram partials
                          + (size_t)NC * NB_ * NN_         // s partials
                          + (size_t)NB_ * NN_              // s_full
                          + (size_t)NB_ * NN_ * NN_        // wq
                          + 2 * 16;                        // loss partials
        if (need <= ws_floats) break;
        NC >>= 1;
    }
    const int KC = HW_ / NC;

    float* gram_part = (float*)d_ws;
    float* s_part    = gram_part + (size_t)NC * NB_ * NN_ * NN_;
    float* s_full    = s_part    + (size_t)NC * NB_ * NN_;
    float* wq        = s_full    + (size_t)NB_ * NN_;
    float* num_part  = wq        + (size_t)NB_ * NN_ * NN_;
    float* den_part  = num_part  + 16;

    gram_kernel<<<NB_ * NC, 256, 0, stream>>>(masks, gram_part, s_part, NC, KC);
    s_reduce_kernel<<<NB_, 64, 0, stream>>>(s_part, s_full, NC);
    cr_weight_kernel<<<dim3(NB_, (NN_ * NN_) / 256), 256, 0, stream>>>(gram_part, s_full, wq, NC);
    loss2_kernel<<<(NN_ * NN_) / 256, 256, 0, stream>>>(wq, nodes, num_part, den_part);
    final_kernel<<<1, 64, 0, stream>>>(num_part, den_part, out);
}

// Round 5
// 42.400 us; speedup vs baseline: 9.2957x; 1.0753x over previous
//
#include <hip/hip_runtime.h>
#include <cstdint>
#include <cstddef>

static constexpr int HW_ = 16384;  // h*w
static constexpr int NB_ = 32;     // batch
static constexpr int NN_ = 64;     // n
static constexpr int BK_ = 64;     // k per staged LDS tile

typedef short bfrag  __attribute__((ext_vector_type(8)));  // 8 bf16 (4 VGPRs)
typedef float f32x4  __attribute__((ext_vector_type(4)));  // MFMA accumulator

// fp32 -> bf16, round-to-nearest-even
__device__ __forceinline__ unsigned short f2bf_rne(float x) {
    unsigned u = __builtin_bit_cast(unsigned, x);
    return (unsigned short)((u + 0x7FFFu + ((u >> 16) & 1u)) >> 16);
}

// XOR-swizzled bf16-element index in a row-major [64][BK_=64] bf16 tile
// (128 B rows). byte ^= (row&7)<<4. Same involution on write+read.
__device__ __forceinline__ int swz(int row, int k) {
    int byte = (row << 7) + (k << 1);
    byte ^= (row & 7) << 4;
    return byte >> 1;
}

__global__ __launch_bounds__(256) void gram_kernel(const float* __restrict__ masks,
                                                   float* __restrict__ gram_part,
                                                   float* __restrict__ s_part,
                                                   int NC, int KC) {
    __shared__ __align__(16) unsigned short lds[2][NN_ * BK_];  // 2 x 8 KiB bf16
    const int bx = blockIdx.x;
    const int b  = bx / NC;
    const int c  = bx - b * NC;
    const int t  = threadIdx.x;        // 256 threads = 4 waves
    const int l  = t & 63;
    const int w  = t >> 6;             // wave id: owns output rows [16w,16w+16)
    const int lrow = t >> 4;           // staging row base 0..15
    const int lk4  = t & 15;           // staging float4 index along k
    const float* mb = masks + (size_t)b * (NN_ * HW_) + (size_t)c * KC;
    const int NT = KC / BK_;

    f32x4 acc[4];
#pragma unroll
    for (int cb = 0; cb < 4; ++cb) acc[cb] = (f32x4){0.f, 0.f, 0.f, 0.f};
    float sreg[4] = {0.f, 0.f, 0.f, 0.f};
    float4 ld[4];

    auto stage_load = [&](int tt) {
        const float* src = mb + tt * BK_ + lk4 * 4;
#pragma unroll
        for (int p = 0; p < 4; ++p)
            ld[p] = *reinterpret_cast<const float4*>(src + (size_t)(lrow + 16 * p) * HW_);
    };
    auto stage_write = [&](unsigned short* buf) {
#pragma unroll
        for (int p = 0; p < 4; ++p) {
            const float m0 = fmaxf(0.f, (ld[p].x + 1.f) * 0.5f);
            const float m1 = fmaxf(0.f, (ld[p].y + 1.f) * 0.5f);
            const float m2 = fmaxf(0.f, (ld[p].z + 1.f) * 0.5f);
            const float m3 = fmaxf(0.f, (ld[p].w + 1.f) * 0.5f);
            sreg[p] += (m0 + m1) + (m2 + m3);
            const ushort4 pk = make_ushort4(f2bf_rne(m0), f2bf_rne(m1),
                                            f2bf_rne(m2), f2bf_rne(m3));
            *reinterpret_cast<ushort4*>(&buf[swz(lrow + 16 * p, lk4 * 4)]) = pk;
        }
    };
    auto compute = [&](const unsigned short* buf) {
#pragma unroll
        for (int ks = 0; ks < BK_; ks += 32) {
            const int kb = ks + ((l >> 4) << 3);
            const bfrag a = *reinterpret_cast<const bfrag*>(&buf[swz((w << 4) + (l & 15), kb)]);
#pragma unroll
            for (int cb = 0; cb < 4; ++cb) {
                const bfrag bb = *reinterpret_cast<const bfrag*>(&buf[swz((cb << 4) + (l & 15), kb)]);
                acc[cb] = __builtin_amdgcn_mfma_f32_16x16x32_bf16(a, bb, acc[cb], 0, 0, 0);
            }
        }
    };

    stage_load(0);
    stage_write(lds[0]);
    __syncthreads();
    for (int tt = 0; tt < NT; ++tt) {
        const int cur = tt & 1;
        const bool more = (tt + 1 < NT);
        if (more) stage_load(tt + 1);         // issue early
        compute(lds[cur]);                    // hide HBM latency under MFMA
        if (more) stage_write(lds[cur ^ 1]);  // write late
        __syncthreads();
    }

    // C/D layout: col = lane&15, row = (lane>>4)*4 + reg
    float* gp = gram_part + (size_t)(c * NB_ + b) * (NN_ * NN_);
#pragma unroll
    for (int cb = 0; cb < 4; ++cb)
#pragma unroll
        for (int r = 0; r < 4; ++r) {
            const int i = (w << 4) + ((l >> 4) << 2) + r;
            const int j = (cb << 4) + (l & 15);
            gp[i * NN_ + j] = acc[cb][r];
        }
#pragma unroll
    for (int p = 0; p < 4; ++p) {
        float v = sreg[p];
        v += __shfl_xor(v, 1, 64);
        v += __shfl_xor(v, 2, 64);
        v += __shfl_xor(v, 4, 64);
        v += __shfl_xor(v, 8, 64);
        if ((l & 15) == 0)
            s_part[(size_t)c * (NB_ * NN_) + b * NN_ + (lrow + 16 * p)] = v;
    }
}

// Epilogue stage 1 (s_reduce fused): per (b, ij-chunk), reduce gram partials
// over c (coalesced), reduce s_part over c into LDS, write wq = g/min(si,sj).
__global__ __launch_bounds__(256) void cr_weight_kernel(const float* __restrict__ gram_part,
                                                        const float* __restrict__ s_part,
                                                        float* __restrict__ wq, int NC) {
    __shared__ float s_loc[NN_];
    const int b = blockIdx.x;                        // 0..31
    if (threadIdx.x < NN_) {
        float v = 0.f;
        for (int c = 0; c < NC; ++c)
            v += s_part[(size_t)c * (NB_ * NN_) + b * NN_ + threadIdx.x];
        s_loc[threadIdx.x] = v;
    }
    __syncthreads();
    const int ij = blockIdx.y * 256 + threadIdx.x;   // 0..4095
    float g = 0.f;
#pragma unroll 8
    for (int c = 0; c < NC; ++c)
        g += gram_part[(size_t)(c * NB_ + b) * (NN_ * NN_) + ij];
    const int i = ij >> 6, j = ij & 63;
    wq[(size_t)b * (NN_ * NN_) + ij] = g / fminf(s_loc[i], s_loc[j]);
}

// Epilogue stage 2 (+final fused via last-block-done): mean over b, mask,
// two-level reduce; last block combines the 16 partials.
__global__ __launch_bounds__(256) void loss2_kernel(const float* __restrict__ wq,
                                                    const int* __restrict__ nodes,
                                                    float* __restrict__ num_part,
                                                    float* __restrict__ den_part,
                                                    unsigned int* __restrict__ counter,
                                                    float* __restrict__ out) {
    __shared__ float red[8];
    __shared__ int is_last;
    const int ij = blockIdx.x * 256 + threadIdx.x;
    float acc = 0.f;
#pragma unroll
    for (int b = 0; b < NB_; ++b)
        acc += wq[(size_t)b * (NN_ * NN_) + ij];
    const float cr = acc * (1.0f / NB_);

    const int i = ij >> 6, j = ij & 63;
    const int ni = nodes[i];
    const int nj = nodes[j];
    const int ti = (ni < 7) ? 0 : ((ni < 9) ? 1 : 2);
    const int tj = (nj < 7) ? 0 : ((nj < 9) ? 1 : 2);
    const bool has_f = (ti == 1) || (tj == 1);
    const bool has_a = (ti == 2) || (tj == 2);
    const bool include = !(has_f && !has_a);
    const float beta = ((ti == 2) != (tj == 2)) ? 1.f : 0.f;
    const float wgt = (include && (j > i)) ? 1.f : 0.f;

    float num = wgt * fabsf(beta - cr);
    float den = wgt;
#pragma unroll
    for (int off = 32; off >= 1; off >>= 1) {
        num += __shfl_xor(num, off, 64);
        den += __shfl_xor(den, off, 64);
    }
    const int wave = threadIdx.x >> 6;
    const int lane = threadIdx.x & 63;
    if (lane == 0) { red[wave] = num; red[4 + wave] = den; }
    __syncthreads();
    if (threadIdx.x == 0) {
        const float bn = red[0] + red[1] + red[2] + red[3];
        const float bd = red[4] + red[5] + red[6] + red[7];
        __hip_atomic_store(&num_part[blockIdx.x], bn, __ATOMIC_RELAXED, __HIP_MEMORY_SCOPE_AGENT);
        __hip_atomic_store(&den_part[blockIdx.x], bd, __ATOMIC_RELAXED, __HIP_MEMORY_SCOPE_AGENT);
        // release our partials / acquire everyone else's (RMW chain on counter)
        const unsigned old = __hip_atomic_fetch_add(counter, 1u, __ATOMIC_ACQ_REL,
                                                    __HIP_MEMORY_SCOPE_AGENT);
        is_last = (old == (unsigned)(gridDim.x - 1));
    }
    __syncthreads();
    if (is_last && threadIdx.x < 64) {
        const int t = threadIdx.x;
        float n16 = 0.f, d16 = 0.f;
        if (t < 16) {
            n16 = __hip_atomic_load(&num_part[t], __ATOMIC_RELAXED, __HIP_MEMORY_SCOPE_AGENT);
            d16 = __hip_atomic_load(&den_part[t], __ATOMIC_RELAXED, __HIP_MEMORY_SCOPE_AGENT);
        }
#pragma unroll
        for (int off = 8; off >= 1; off >>= 1) {
            n16 += __shfl_xor(n16, off, 64);
            d16 += __shfl_xor(d16, off, 64);
        }
        if (t == 0) out[0] = n16 / d16;
    }
}

extern "C" void kernel_launch(void* const* d_in, const int* in_sizes, int n_in,
                              void* d_out, int out_size, void* d_ws, size_t ws_size,
                              hipStream_t stream) {
    const float* masks = (const float*)d_in[0];
    const int* nodes = (const int*)d_in[1];   // harness passes integers as int32
    float* out = (float*)d_out;

    const size_t ws_floats = ws_size / sizeof(float);
    int NC = 16;
    while (NC > 1) {
        const size_t need = (size_t)NC * NB_ * NN_ * NN_   // gram partials
                          + (size_t)NC * NB_ * NN_         // s partials
                          + (size_t)NB_ * NN_ * NN_        // wq
                          + 2 * 16 + 4;                    // partials + counter
        if (need <= ws_floats) break;
        NC >>= 1;
    }
    const int KC = HW_ / NC;

    float* gram_part = (float*)d_ws;
    float* s_part    = gram_part + (size_t)NC * NB_ * NN_ * NN_;
    float* wq        = s_part    + (size_t)NC * NB_ * NN_;
    float* num_part  = wq        + (size_t)NB_ * NN_ * NN_;
    float* den_part  = num_part  + 16;
    unsigned int* counter = (unsigned int*)(den_part + 16);

    hipMemsetAsync(counter, 0, sizeof(unsigned int), stream);
    gram_kernel<<<NB_ * NC, 256, 0, stream>>>(masks, gram_part, s_part, NC, KC);
    cr_weight_kernel<<<dim3(NB_, (NN_ * NN_) / 256), 256, 0, stream>>>(gram_part, s_part, wq, NC);
    loss2_kernel<<<(NN_ * NN_) / 256, 256, 0, stream>>>(wq, nodes, num_part, den_part, counter, out);
}